// Round 7
// baseline (441.384 us; speedup 1.0000x reference)
//
#include <hip/hip_runtime.h>
#include <hip/hip_bf16.h>
#include <cstdint>
#include <cstddef>

#define S_LEN   2048
#define NHQ     16
#define NKV_H   8
#define HD_DIM  128
#define DMODEL  2048
#define BATCH   2
#define KVD     (NKV_H * HD_DIM)   // 1024
#define QKV_LD  4096               // interleaved [M][q(2048) | k(1024) | v(1024)]

typedef float f32x4  __attribute__((ext_vector_type(4)));
typedef __bf16 bf16x8 __attribute__((ext_vector_type(8)));
typedef __bf16 bf16x4 __attribute__((ext_vector_type(4)));
typedef short  s16x4  __attribute__((ext_vector_type(4)));

// ---------------------------------------------------------------------------
// async 16B global -> LDS (lane's 16B lands at ldsbase + lane*16)
// ---------------------------------------------------------------------------
__device__ __forceinline__ void gload_lds16(const __bf16* g, __bf16* l) {
    __builtin_amdgcn_global_load_lds(
        (const __attribute__((address_space(1))) void*)g,
        (__attribute__((address_space(3))) void*)l, 16, 0, 0);
}

// ---------------------------------------------------------------------------
// Combined tiny prep kernel: block 0 = sniff x dtype, block 1 = sniff fc
// dtype, block 2 = mask normalization (layout sniff + to u8).
// ---------------------------------------------------------------------------
__global__ __launch_bounds__(256)
void prep_kernel(const unsigned* __restrict__ x, int* __restrict__ flag_x,
                 const unsigned* __restrict__ fc, int* __restrict__ flag_fc,
                 const unsigned char* __restrict__ mraw,
                 unsigned char* __restrict__ mout, int n) {
    if (blockIdx.x == 0) {
        __shared__ int cnt;
        if (threadIdx.x == 0) cnt = 0;
        __syncthreads();
        int c = 0;
        for (int j = threadIdx.x; j < 1024; j += 256) {
            unsigned hw = x[j] & 0xFFFFu;
            unsigned e  = (hw >> 7) & 0xFF;
            if (hw == 0u || (e >= 118 && e <= 132)) c++;
        }
        atomicAdd(&cnt, c);
        __syncthreads();
        if (threadIdx.x == 0) *flag_x = (cnt > 512) ? 1 : 0;
    } else if (blockIdx.x == 1) {
        if (threadIdx.x == 0) *flag_fc = (fc[0] == 0x3F803F80u) ? 1 : 0;
    } else {
        __shared__ int f_bf16, f_f32, f_u8;
        if (threadIdx.x == 0) { f_bf16 = 0; f_f32 = 0; f_u8 = 0; }
        __syncthreads();
        const unsigned* dw = (const unsigned*)mraw;
        int ndw = n / 4;
        for (int j = threadIdx.x; j < ndw; j += blockDim.x) {
            unsigned v = dw[j];
            if (v == 0x00003F80u || v == 0x3F803F80u) f_bf16 = 1;
            else if (v == 0x3F800000u) f_f32 = 1;
            else if (v & 0xFFFFFFFEu) f_u8 = 1;
        }
        __syncthreads();
        int layout;              // 0=u8 1=i32 2=f32 3=bf16
        if (f_bf16) layout = 3;
        else if (f_f32) layout = 2;
        else if (f_u8) layout = 0;
        else layout = 1;
        for (int i = threadIdx.x; i < n; i += blockDim.x) {
            unsigned v;
            if (layout == 0)      v = mraw[i];
            else if (layout == 3) v = ((const unsigned short*)mraw)[i];
            else                  v = ((const unsigned*)mraw)[i];
            mout[i] = v ? 1u : 0u;
        }
    }
}

// ---------------------------------------------------------------------------
// Convert helper: 8 elems from src+off (f32 or bf16 by flag) -> bf16 dst.
// ---------------------------------------------------------------------------
__device__ __forceinline__ void conv8(const void* src, __bf16* dst,
                                      size_t off, int isbf16) {
    if (isbf16) {
        *reinterpret_cast<uint4*>(dst + off) =
            *reinterpret_cast<const uint4*>((const __bf16*)src + off);
    } else {
        const float* f = (const float*)src + off;
        float4 a = *reinterpret_cast<const float4*>(f);
        float4 b = *reinterpret_cast<const float4*>(f + 4);
        bf16x8 v;
        v[0] = (__bf16)a.x; v[1] = (__bf16)a.y; v[2] = (__bf16)a.z; v[3] = (__bf16)a.w;
        v[4] = (__bf16)b.x; v[5] = (__bf16)b.y; v[6] = (__bf16)b.z; v[7] = (__bf16)b.w;
        *reinterpret_cast<bf16x8*>(dst + off) = v;
    }
}

// ---------------------------------------------------------------------------
// One launch converts x -> xb and wq|wk|wv -> wcomb (contiguous dest).
// n8 ranges: x 1048576, wq 524288, wk 262144, wv 262144 (grid 8192 exact).
// ---------------------------------------------------------------------------
__global__ __launch_bounds__(256)
void conv_all_kernel(const void* __restrict__ x,  const void* __restrict__ wq,
                     const void* __restrict__ wk, const void* __restrict__ wv,
                     __bf16* __restrict__ xb, __bf16* __restrict__ wcomb,
                     const int* __restrict__ dflag) {
    int i = blockIdx.x * 256 + threadIdx.x;
    int isb = *dflag;
    if (i < 1048576) {
        conv8(x, xb, (size_t)i * 8, isb);
    } else if (i < 1572864) {
        conv8(wq, wcomb, (size_t)(i - 1048576) * 8, isb);
    } else if (i < 1835008) {
        conv8(wk, wcomb + (size_t)2048 * 2048, (size_t)(i - 1572864) * 8, isb);
    } else {
        conv8(wv, wcomb + (size_t)3072 * 2048, (size_t)(i - 1835008) * 8, isb);
    }
}

// ---------------------------------------------------------------------------
// Strided conv for wo: src [2048][2048], dst row n at n*QKV_LD (dead k/v
// columns of qkv, written only after attn completes).
// ---------------------------------------------------------------------------
__global__ __launch_bounds__(256)
void conv_bf16_strided_kernel(const void* __restrict__ src,
                              __bf16* __restrict__ dstbase,
                              int n8, const int* __restrict__ dflag) {
    int i = blockIdx.x * blockDim.x + threadIdx.x;
    if (i >= n8) return;
    size_t off = (size_t)i * 8;
    size_t row = off >> 11;          // / 2048
    size_t col = off & 2047;
    __bf16* dst = dstbase + row * QKV_LD + col;
    if (*dflag) {
        *reinterpret_cast<uint4*>(dst) =
            *reinterpret_cast<const uint4*>((const __bf16*)src + off);
    } else {
        const float* f = (const float*)src + off;
        float4 a = *reinterpret_cast<const float4*>(f);
        float4 b = *reinterpret_cast<const float4*>(f + 4);
        bf16x8 v;
        v[0] = (__bf16)a.x; v[1] = (__bf16)a.y; v[2] = (__bf16)a.z; v[3] = (__bf16)a.w;
        v[4] = (__bf16)b.x; v[5] = (__bf16)b.y; v[6] = (__bf16)b.z; v[7] = (__bf16)b.w;
        *reinterpret_cast<bf16x8*>(dst) = v;
    }
}

// ---------------------------------------------------------------------------
// m97-style MFMA GEMM: C = A @ Bw^T, bf16 in, fp32 acc. Runtime lda/ldb/ldc.
// Bijective XCD swizzle (T1): grid sizes are multiples of 8.
// ---------------------------------------------------------------------------
template <bool OUT_BF16>
__global__ __launch_bounds__(256)
void gemm_bt_async(const __bf16* __restrict__ A, const __bf16* __restrict__ Bw,
                   void* __restrict__ Cv, int K, int lda, int ldb, int ldc) {
    __shared__ __align__(16) __bf16 As[128 * 64];
    __shared__ __align__(16) __bf16 Bs[128 * 64];

    const int t    = threadIdx.x;
    const int w    = t >> 6;
    const int lane = t & 63;
    const int quad = lane >> 4;
    const int l16  = lane & 15;
    const int wm   = (w >> 1) * 64;
    const int wn   = (w & 1) * 64;

    // XCD-aware swizzle over the linearized grid (x fastest)
    const int nwg  = gridDim.x * gridDim.y;
    const int lin  = blockIdx.y * gridDim.x + blockIdx.x;
    const int swz  = (lin & 7) * (nwg >> 3) + (lin >> 3);
    const int m0   = (swz % gridDim.x) * 128;
    const int n0   = (swz / gridDim.x) * 128;

    const int rl   = lane >> 3;
    const int gl   = lane & 7;

    f32x4 acc[4][4];
#pragma unroll
    for (int i = 0; i < 4; ++i)
#pragma unroll
        for (int j = 0; j < 4; ++j) acc[i][j] = (f32x4){0.f, 0.f, 0.f, 0.f};

    for (int k0 = 0; k0 < K; k0 += 64) {
        __syncthreads();
#pragma unroll
        for (int p = 0; p < 4; ++p) {
            const int rowb = w * 32 + p * 8;
            const int r    = rowb + rl;
            const int gA   = gl ^ rl;
            gload_lds16(A  + (size_t)(m0 + r) * lda + k0 + gA * 8, &As[rowb * 64]);
            gload_lds16(Bw + (size_t)(n0 + r) * ldb + k0 + gA * 8, &Bs[rowb * 64]);
        }
        __syncthreads();
#pragma unroll
        for (int ks = 0; ks < 2; ++ks) {
            const int G = ks * 4 + quad;
            const int gsw = (G ^ (l16 & 7)) * 8;
            bf16x8 af[4], bf[4];
#pragma unroll
            for (int i = 0; i < 4; ++i)
                af[i] = *reinterpret_cast<const bf16x8*>(
                    &As[(wm + i * 16 + l16) * 64 + gsw]);
#pragma unroll
            for (int j = 0; j < 4; ++j)
                bf[j] = *reinterpret_cast<const bf16x8*>(
                    &Bs[(wn + j * 16 + l16) * 64 + gsw]);
#pragma unroll
            for (int i = 0; i < 4; ++i)
#pragma unroll
                for (int j = 0; j < 4; ++j)
                    acc[i][j] = __builtin_amdgcn_mfma_f32_16x16x32_bf16(
                        af[i], bf[j], acc[i][j], 0, 0, 0);
        }
    }
#pragma unroll
    for (int i = 0; i < 4; ++i)
#pragma unroll
        for (int r = 0; r < 4; ++r) {
            size_t m = (size_t)(m0 + wm + i * 16 + quad * 4 + r);
#pragma unroll
            for (int j = 0; j < 4; ++j) {
                int n = n0 + wn + j * 16 + l16;
                if constexpr (OUT_BF16)
                    ((__hip_bfloat16*)Cv)[m * ldc + n] = __float2bfloat16(acc[i][j][r]);
                else
                    ((float*)Cv)[m * ldc + n] = acc[i][j][r];
            }
        }
}

// ---------------------------------------------------------------------------
// RoPE in-place on interleaved qkv: heads 0..15 = Q, 16..23 = K (cols 0..3071
// at stride QKV_LD). One launch covers both. Pair i rotates (2i, 2i+1).
// ---------------------------------------------------------------------------
__global__ void rope_kernel(__hip_bfloat16* __restrict__ xqk,
                            const void* __restrict__ cosv,
                            const void* __restrict__ sinv,
                            const int* __restrict__ dflag_fc,
                            int npairs) {
    int idx = blockIdx.x * blockDim.x + threadIdx.x;
    if (idx >= npairs) return;
    int i  = idx & 63;
    int h  = (idx >> 6) % 24;
    int bs = idx / (64 * 24);
    int s  = bs & (S_LEN - 1);
    float c, sn;
    if (*dflag_fc) {
        c  = __bfloat162float(((const __hip_bfloat16*)cosv)[s * 64 + i]);
        sn = __bfloat162float(((const __hip_bfloat16*)sinv)[s * 64 + i]);
    } else {
        c  = ((const float*)cosv)[s * 64 + i];
        sn = ((const float*)sinv)[s * 64 + i];
    }
    unsigned* p = (unsigned*)(xqk + (size_t)bs * QKV_LD + h * HD_DIM) + i;
    unsigned u = *p;
    float xr = __uint_as_float(u << 16);
    float xi = __uint_as_float(u & 0xFFFF0000u);
    float o0 = xr * c - xi * sn;
    float o1 = xr * sn + xi * c;
    union { __hip_bfloat16 h2[2]; unsigned u32; } out;
    out.h2[0] = __float2bfloat16(o0);
    out.h2[1] = __float2bfloat16(o1);
    *p = out.u32;
}

// ---------------------------------------------------------------------------
// V transpose: qkv v-cols (stride QKV_LD) -> vt [(b*NKV+kv)*128 + d][S].
// ---------------------------------------------------------------------------
__global__ __launch_bounds__(256)
void transpose_v_kernel(const __hip_bfloat16* __restrict__ xv,
                        __hip_bfloat16* __restrict__ vt) {
    __shared__ unsigned short T[32][36];
    const int t  = threadIdx.x;
    const int s0 = blockIdx.x * 32;
    const int d0 = blockIdx.y * 32;
    const int z  = blockIdx.z;           // b*NKV + kv
    const int b  = z >> 3;
    const int kv = z & 7;
    {
        int sr = t >> 3, dc = (t & 7) * 4;
        const unsigned short* p = (const unsigned short*)xv
            + (size_t)(b * S_LEN + s0 + sr) * QKV_LD + kv * 128 + d0 + dc;
        uint2 v = *reinterpret_cast<const uint2*>(p);
        T[sr][dc + 0] = (unsigned short)(v.x & 0xFFFFu);
        T[sr][dc + 1] = (unsigned short)(v.x >> 16);
        T[sr][dc + 2] = (unsigned short)(v.y & 0xFFFFu);
        T[sr][dc + 3] = (unsigned short)(v.y >> 16);
    }
    __syncthreads();
    {
        int dr = t >> 3, sc = (t & 7) * 4;
        unsigned w0 = (unsigned)T[sc + 0][dr] | ((unsigned)T[sc + 1][dr] << 16);
        unsigned w1 = (unsigned)T[sc + 2][dr] | ((unsigned)T[sc + 3][dr] << 16);
        unsigned short* q = (unsigned short*)vt
            + ((size_t)z * 128 + d0 + dr) * S_LEN + s0 + sc;
        uint2 v; v.x = w0; v.y = w1;
        *reinterpret_cast<uint2*>(q) = v;
    }
}

// ---------------------------------------------------------------------------
// MFMA flash attention v9 = v8 + in-register P (no Ps LDS round-trip):
// Swapped QK^T leaves lane (quad,l16) holding P[q=l16][key=n0*16+quad*4+r],
// which IS the A-fragment layout of v_mfma_f32_16x16x16_bf16 (row=l16,
// k=quad*4+reg). PV becomes 4(n0) x 8(d0) MFMAs of 16x16x16 with A straight
// from registers; B = 4 consecutive bf16 from Vt row d0*16+l16 (ds_read_b64,
// 2-way bank-safe under the granule swizzle). Removes: P-store (b64 x4),
// af reads (b128 x2), the same-wave ds_write->ds_read bubble, the Ps bank
// conflicts, and 8 KB LDS (72->64 KB).
// ---------------------------------------------------------------------------
__global__ __launch_bounds__(256)
void attn_mfma2_kernel(__hip_bfloat16* qkv,
                       const __hip_bfloat16* __restrict__ vt_g,
                       const unsigned char* __restrict__ msk) {
    __shared__ __align__(16) __bf16 Ks[2][64 * 128];  // 32768 B
    __shared__ __align__(16) __bf16 Vt[2][128 * 64];  // 32768 B -> 65536 total

    const int t    = threadIdx.x;
    const int w    = t >> 6;
    const int lane = t & 63;
    const int quad = lane >> 4;
    const int l16  = lane & 15;

    // XCD swizzle: 1024 blocks, chunk=128 -> one XCD covers 4 heads' q-tiles
    const int bid = ((blockIdx.x & 7) << 7) | (blockIdx.x >> 3);
    const int qt  = bid & 31;
    const int h   = (bid >> 5) & (NHQ - 1);
    const int b   = bid >> 9;
    const int kvh = h >> 1;
    const int q0  = qt * 64;

    // ---- Q fragments in registers: wave w owns q rows w*16..w*16+15 ----
    bf16x8 qf[4];
    {
        const __bf16* qrow = (const __bf16*)qkv
            + (size_t)(b * S_LEN + q0 + w * 16 + l16) * QKV_LD + h * 128 + quad * 8;
#pragma unroll
        for (int ks = 0; ks < 4; ++ks)
            qf[ks] = *reinterpret_cast<const bf16x8*>(qrow + ks * 32);
    }

    // per-lane softmax state for q-row l16 (replicated across the 4 quads)
    float m_r = -INFINITY, l_r = 0.f;
    f32x4 o[8];
#pragma unroll
    for (int d0 = 0; d0 < 8; ++d0) o[d0] = (f32x4){0.f, 0.f, 0.f, 0.f};

    const float scale2 = 0.08838834764831845f * 1.4426950408889634f;
    const int gbase = lane & 48;

    // ---- persistent staging pointers (bumped per staged tile) ----
    const __bf16* kp[4];
    const __bf16* vp[4];
    {
        const __bf16* xk = (const __bf16*)qkv + 2048;
        const int krl = lane >> 4, kgl = lane & 15;
        const int vrl = lane >> 3, vgl = lane & 7;
#pragma unroll
        for (int p = 0; p < 4; ++p) {
            const int row = w * 16 + p * 4 + krl;
            kp[p] = xk + (size_t)(b * S_LEN + row) * QKV_LD
                       + kvh * 128 + (kgl ^ (row & 7)) * 8;
        }
#pragma unroll
        for (int p = 0; p < 4; ++p) {
            const int row = w * 32 + p * 8 + vrl;
            vp[p] = (const __bf16*)vt_g
                  + ((size_t)(b * NKV_H + kvh) * 128 + row) * S_LEN
                  + (vgl ^ (row & 7)) * 8;
        }
    }
    const unsigned char* mbase = msk + b * S_LEN;

    // stage one 64-key tile (K + V^T) into buffer sb and advance pointers
    auto stage = [&](int sb) {
#pragma unroll
        for (int p = 0; p < 4; ++p) {
            gload_lds16(kp[p], &Ks[sb][(w * 16 + p * 4) * 128]);
            kp[p] += 64 * QKV_LD;
        }
#pragma unroll
        for (int p = 0; p < 4; ++p) {
            gload_lds16(vp[p], &Vt[sb][(w * 32 + p * 8) * 64]);
            vp[p] += 64;
        }
    };

    // compute one 64-key tile from buffer cb; stage next into sb first
    auto tile_body = [&](int kmask, int cb, int sb, bool do_stage) {
        if (do_stage) stage(sb);

        unsigned mk4[4];
        {
            const unsigned* mp = (const unsigned*)(mbase + kmask);
#pragma unroll
            for (int n0 = 0; n0 < 4; ++n0) mk4[n0] = mp[n0 * 4 + quad];
        }

        // ---- swapped QK^T: lane(quad,l16) gets q=l16, k=n0*16+quad*4+r ----
        f32x4 sc4[4];
#pragma unroll
        for (int n0 = 0; n0 < 4; ++n0) sc4[n0] = (f32x4){0.f, 0.f, 0.f, 0.f};
        __builtin_amdgcn_s_setprio(1);
#pragma unroll
        for (int ks = 0; ks < 4; ++ks) {
            const int G = ks * 4 + quad;
#pragma unroll
            for (int n0 = 0; n0 < 4; ++n0) {
                const int row  = n0 * 16 + l16;
                const int slot = G ^ (row & 7);
                bf16x8 kf = *reinterpret_cast<const bf16x8*>(&Ks[cb][row * 128 + slot * 8]);
                sc4[n0] = __builtin_amdgcn_mfma_f32_16x16x32_bf16(kf, qf[ks], sc4[n0], 0, 0, 0);
            }
        }
        __builtin_amdgcn_s_setprio(0);

        // ---- mask (raw scores); reg r <-> key n0*16+quad*4+r ----
#pragma unroll
        for (int n0 = 0; n0 < 4; ++n0)
#pragma unroll
            for (int r = 0; r < 4; ++r)
                sc4[n0][r] = ((mk4[n0] >> (r * 8)) & 0xFF) ? -INFINITY : sc4[n0][r];

        // ---- tile max for own q-row: in-register tree + 2 cross-quad shuffles
        float tq[4];
#pragma unroll
        for (int n0 = 0; n0 < 4; ++n0)
            tq[n0] = fmaxf(fmaxf(sc4[n0][0], sc4[n0][1]),
                           fmaxf(sc4[n0][2], sc4[n0][3]));
        float rm = fmaxf(fmaxf(tq[0], tq[1]), fmaxf(tq[2], tq[3]));
        rm = fmaxf(rm, __shfl_xor(rm, 16, 64));
        rm = fmaxf(rm, __shfl_xor(rm, 32, 64));

        // ---- defer-max: rescale only when max grew past THR=8 (log2 units) ----
        bool need = (rm - m_r) * scale2 > 8.0f;
        if (__any((int)need)) {
            float mn = fmaxf(m_r, rm);
            float al = exp2f((m_r - mn) * scale2);   // 0 on first tile
            m_r = mn;
            l_r *= al;
            float alq[4];
#pragma unroll
            for (int r = 0; r < 4; ++r)
                alq[r] = __shfl(al, gbase | (quad * 4 + r), 64);
#pragma unroll
            for (int d0 = 0; d0 < 8; ++d0)
#pragma unroll
                for (int r = 0; r < 4; ++r) o[d0][r] *= alq[r];
        }

        // ---- p = exp2(...); per-lane partial l; pack A-fragments in regs ----
        s16x4 pa[4];
        float negm = -m_r * scale2;
#pragma unroll
        for (int n0 = 0; n0 < 4; ++n0) {
            bf16x4 pk;
#pragma unroll
            for (int r = 0; r < 4; ++r) {
                float p = exp2f(fmaf(sc4[n0][r], scale2, negm));
                l_r += p;
                pk[r] = (__bf16)p;
            }
            pa[n0] = *reinterpret_cast<s16x4*>(&pk);
        }

        // ---- PV via 16x16x16 MFMA: A = pa (in regs), B = Vt b64 reads ----
        __builtin_amdgcn_s_setprio(1);
#pragma unroll
        for (int n0 = 0; n0 < 4; ++n0) {
            const int j    = n0 * 16 + quad * 4;   // key offset in 64-tile
            const int gran = j >> 3;               // granule 0..7
            const int hb   = (j & 7) * 2;          // byte offset in granule
#pragma unroll
            for (int d0 = 0; d0 < 8; ++d0) {
                const int row  = d0 * 16 + l16;
                const int slot = gran ^ (row & 7);
                s16x4 vb = *reinterpret_cast<const s16x4*>(
                    (const char*)(&Vt[cb][row * 64]) + slot * 16 + hb);
                o[d0] = __builtin_amdgcn_mfma_f32_16x16x16bf16_1k(
                    pa[n0], vb, o[d0], 0, 0, 0);
            }
        }
        __builtin_amdgcn_s_setprio(0);

        __syncthreads();   // drains vmcnt (next tile staged) + all LDS reads
    };

    // ---- prologue: stage tile 0 into buf 0 ----
    stage(0);
    __syncthreads();

    // ---- main loop: 2 tiles per iteration, compile-time buffer indices ----
    for (int k0 = 0; k0 < S_LEN; k0 += 128) {
        tile_body(k0,      0, 1, true);
        tile_body(k0 + 64, 1, 0, k0 + 128 < S_LEN);
    }

    // ---- epilogue: reduce l across quads, redistribute to o-rows, write ----
    float ls = l_r;
    ls += __shfl_xor(ls, 16, 64);
    ls += __shfl_xor(ls, 32, 64);
    float invl = 1.f / ls;
    float invq[4];
#pragma unroll
    for (int r = 0; r < 4; ++r)
        invq[r] = __shfl(invl, gbase | (quad * 4 + r), 64);
    __hip_bfloat16* att = qkv;   // own Q cols, own rows only: safe alias
#pragma unroll
    for (int d0 = 0; d0 < 8; ++d0)
#pragma unroll
        for (int r = 0; r < 4; ++r) {
            size_t row = (size_t)(b * S_LEN + q0 + w * 16 + quad * 4 + r);
            att[row * QKV_LD + h * 128 + d0 * 16 + l16] =
                __float2bfloat16(o[d0][r] * invq[r]);
        }
}

// ---------------------------------------------------------------------------
extern "C" void kernel_launch(void* const* d_in, const int* in_sizes, int n_in,
                              void* d_out, int out_size, void* d_ws, size_t ws_size,
                              hipStream_t stream) {
    const void* x  = d_in[0];
    const void* wq = d_in[1];
    const void* wk = d_in[2];
    const void* wv = d_in[3];
    const void* wo = d_in[4];
    const void* fc = d_in[5];
    const void* fs = d_in[6];
    const unsigned char* mraw = (const unsigned char*)d_in[7];

    const int M = BATCH * S_LEN;                                 // 4096
    // ws (32 MB + 8 KB): control, then interleaved qkv [4096][QKV_LD] bf16.
    // att aliases the Q columns; wo-bf16 lands in the k/v columns post-attn.
    char* wsb = (char*)d_ws;
    int* dflag_x  = (int*)wsb;
    int* dflag_fc = (int*)(wsb + 64);
    unsigned char* mnorm = (unsigned char*)(wsb + 128);
    __hip_bfloat16* qkv = (__hip_bfloat16*)(wsb + 8192);

    // d_out (32 MB f32) as staging scratch before its final write:
    // xb [0,16M), combined weights wq|wk|wv [16M,32M); vt reuses [0,8M) later.
    char* dob = (char*)d_out;
    __bf16* xb    = (__bf16*)dob;
    __bf16* wcomb = (__bf16*)(dob + (16u << 20));   // 4096 rows x 2048 cols
    __hip_bfloat16* vt = (__hip_bfloat16*)d_out;

    hipLaunchKernelGGL(prep_kernel, dim3(3), dim3(256), 0, stream,
                       (const unsigned*)x, dflag_x, (const unsigned*)fc, dflag_fc,
                       mraw, mnorm, BATCH * S_LEN);

    hipLaunchKernelGGL(conv_all_kernel, dim3(8192), dim3(256), 0, stream,
                       x, wq, wk, wv, xb, wcomb, dflag_x);

    // ---- fused QKV projection: [4096]x[4096]x[2048], 1024 blocks ----
    hipLaunchKernelGGL((gemm_bt_async<true>), dim3(M / 128, QKV_LD / 128), dim3(256), 0, stream,
                       xb, wcomb, (void*)qkv, DMODEL, DMODEL, DMODEL, QKV_LD);

    // ---- single RoPE over Q+K heads (0..23) ----
    int npairs = M * 24 * (HD_DIM / 2);
    hipLaunchKernelGGL(rope_kernel, dim3(npairs / 256), dim3(256), 0, stream,
                       qkv, fc, fs, dflag_fc, npairs);

    hipLaunchKernelGGL(transpose_v_kernel, dim3(S_LEN / 32, HD_DIM / 32, BATCH * NKV_H),
                       dim3(256), 0, stream, qkv + 3072, vt);

    hipLaunchKernelGGL(attn_mfma2_kernel, dim3(BATCH * NHQ * (S_LEN / 64)), dim3(256), 0, stream,
                       qkv, vt, mnorm);

    // ---- wo -> bf16 into dead k/v columns (after attn finished reading K) ----
    hipLaunchKernelGGL(conv_bf16_strided_kernel, dim3((DMODEL * DMODEL / 8) / 256), dim3(256), 0, stream,
                       wo, (__bf16*)qkv + 2048, DMODEL * DMODEL / 8, dflag_x);

    // ---- O-projection: A = att (Q cols, lda=QKV_LD), B = wo (ldb=QKV_LD) ----
    hipLaunchKernelGGL((gemm_bt_async<false>), dim3(M / 128, DMODEL / 128), dim3(256), 0, stream,
                       (const __bf16*)qkv, (const __bf16*)qkv + 2048, d_out,
                       DMODEL, QKV_LD, QKV_LD, DMODEL);
}

// Round 8
// 426.832 us; speedup vs baseline: 1.0341x; 1.0341x over previous
//
#include <hip/hip_runtime.h>
#include <hip/hip_bf16.h>
#include <cstdint>
#include <cstddef>

#define S_LEN   2048
#define NHQ     16
#define NKV_H   8
#define HD_DIM  128
#define DMODEL  2048
#define BATCH   2
#define KVD     (NKV_H * HD_DIM)   // 1024
#define QKV_LD  4096               // interleaved [M][q(2048) | k(1024) | v(1024)]

typedef float f32x4  __attribute__((ext_vector_type(4)));
typedef __bf16 bf16x8 __attribute__((ext_vector_type(8)));
typedef __bf16 bf16x4 __attribute__((ext_vector_type(4)));

// ---------------------------------------------------------------------------
// async 16B global -> LDS (lane's 16B lands at ldsbase + lane*16)
// ---------------------------------------------------------------------------
__device__ __forceinline__ void gload_lds16(const __bf16* g, __bf16* l) {
    __builtin_amdgcn_global_load_lds(
        (const __attribute__((address_space(1))) void*)g,
        (__attribute__((address_space(3))) void*)l, 16, 0, 0);
}

// ---------------------------------------------------------------------------
// Combined tiny prep kernel: block 0 = sniff x dtype, block 1 = sniff fc
// dtype, block 2 = mask normalization (layout sniff + to u8).
// ---------------------------------------------------------------------------
__global__ __launch_bounds__(256)
void prep_kernel(const unsigned* __restrict__ x, int* __restrict__ flag_x,
                 const unsigned* __restrict__ fc, int* __restrict__ flag_fc,
                 const unsigned char* __restrict__ mraw,
                 unsigned char* __restrict__ mout, int n) {
    if (blockIdx.x == 0) {
        __shared__ int cnt;
        if (threadIdx.x == 0) cnt = 0;
        __syncthreads();
        int c = 0;
        for (int j = threadIdx.x; j < 1024; j += 256) {
            unsigned hw = x[j] & 0xFFFFu;
            unsigned e  = (hw >> 7) & 0xFF;
            if (hw == 0u || (e >= 118 && e <= 132)) c++;
        }
        atomicAdd(&cnt, c);
        __syncthreads();
        if (threadIdx.x == 0) *flag_x = (cnt > 512) ? 1 : 0;
    } else if (blockIdx.x == 1) {
        if (threadIdx.x == 0) *flag_fc = (fc[0] == 0x3F803F80u) ? 1 : 0;
    } else {
        __shared__ int f_bf16, f_f32, f_u8;
        if (threadIdx.x == 0) { f_bf16 = 0; f_f32 = 0; f_u8 = 0; }
        __syncthreads();
        const unsigned* dw = (const unsigned*)mraw;
        int ndw = n / 4;
        for (int j = threadIdx.x; j < ndw; j += blockDim.x) {
            unsigned v = dw[j];
            if (v == 0x00003F80u || v == 0x3F803F80u) f_bf16 = 1;
            else if (v == 0x3F800000u) f_f32 = 1;
            else if (v & 0xFFFFFFFEu) f_u8 = 1;
        }
        __syncthreads();
        int layout;              // 0=u8 1=i32 2=f32 3=bf16
        if (f_bf16) layout = 3;
        else if (f_f32) layout = 2;
        else if (f_u8) layout = 0;
        else layout = 1;
        for (int i = threadIdx.x; i < n; i += blockDim.x) {
            unsigned v;
            if (layout == 0)      v = mraw[i];
            else if (layout == 3) v = ((const unsigned short*)mraw)[i];
            else                  v = ((const unsigned*)mraw)[i];
            mout[i] = v ? 1u : 0u;
        }
    }
}

// ---------------------------------------------------------------------------
// Convert helper: 8 elems from src+off (f32 or bf16 by flag) -> bf16 dst.
// ---------------------------------------------------------------------------
__device__ __forceinline__ void conv8(const void* src, __bf16* dst,
                                      size_t off, int isbf16) {
    if (isbf16) {
        *reinterpret_cast<uint4*>(dst + off) =
            *reinterpret_cast<const uint4*>((const __bf16*)src + off);
    } else {
        const float* f = (const float*)src + off;
        float4 a = *reinterpret_cast<const float4*>(f);
        float4 b = *reinterpret_cast<const float4*>(f + 4);
        bf16x8 v;
        v[0] = (__bf16)a.x; v[1] = (__bf16)a.y; v[2] = (__bf16)a.z; v[3] = (__bf16)a.w;
        v[4] = (__bf16)b.x; v[5] = (__bf16)b.y; v[6] = (__bf16)b.z; v[7] = (__bf16)b.w;
        *reinterpret_cast<bf16x8*>(dst + off) = v;
    }
}

// ---------------------------------------------------------------------------
// One launch converts x -> xb and wq|wk|wv -> wcomb (contiguous dest).
// n8 ranges: x 1048576, wq 524288, wk 262144, wv 262144 (grid 8192 exact).
// ---------------------------------------------------------------------------
__global__ __launch_bounds__(256)
void conv_all_kernel(const void* __restrict__ x,  const void* __restrict__ wq,
                     const void* __restrict__ wk, const void* __restrict__ wv,
                     __bf16* __restrict__ xb, __bf16* __restrict__ wcomb,
                     const int* __restrict__ dflag) {
    int i = blockIdx.x * 256 + threadIdx.x;
    int isb = *dflag;
    if (i < 1048576) {
        conv8(x, xb, (size_t)i * 8, isb);
    } else if (i < 1572864) {
        conv8(wq, wcomb, (size_t)(i - 1048576) * 8, isb);
    } else if (i < 1835008) {
        conv8(wk, wcomb + (size_t)2048 * 2048, (size_t)(i - 1572864) * 8, isb);
    } else {
        conv8(wv, wcomb + (size_t)3072 * 2048, (size_t)(i - 1835008) * 8, isb);
    }
}

// ---------------------------------------------------------------------------
// Strided conv for wo: src [2048][2048], dst row n at n*QKV_LD (dead k/v
// columns of qkv, written only after attn completes).
// ---------------------------------------------------------------------------
__global__ __launch_bounds__(256)
void conv_bf16_strided_kernel(const void* __restrict__ src,
                              __bf16* __restrict__ dstbase,
                              int n8, const int* __restrict__ dflag) {
    int i = blockIdx.x * blockDim.x + threadIdx.x;
    if (i >= n8) return;
    size_t off = (size_t)i * 8;
    size_t row = off >> 11;          // / 2048
    size_t col = off & 2047;
    __bf16* dst = dstbase + row * QKV_LD + col;
    if (*dflag) {
        *reinterpret_cast<uint4*>(dst) =
            *reinterpret_cast<const uint4*>((const __bf16*)src + off);
    } else {
        const float* f = (const float*)src + off;
        float4 a = *reinterpret_cast<const float4*>(f);
        float4 b = *reinterpret_cast<const float4*>(f + 4);
        bf16x8 v;
        v[0] = (__bf16)a.x; v[1] = (__bf16)a.y; v[2] = (__bf16)a.z; v[3] = (__bf16)a.w;
        v[4] = (__bf16)b.x; v[5] = (__bf16)b.y; v[6] = (__bf16)b.z; v[7] = (__bf16)b.w;
        *reinterpret_cast<bf16x8*>(dst) = v;
    }
}

// ---------------------------------------------------------------------------
// m97-style MFMA GEMM: C = A @ Bw^T, bf16 in, fp32 acc. Runtime lda/ldb/ldc.
// Bijective XCD swizzle (T1): grid sizes are multiples of 8.
// ---------------------------------------------------------------------------
template <bool OUT_BF16>
__global__ __launch_bounds__(256)
void gemm_bt_async(const __bf16* __restrict__ A, const __bf16* __restrict__ Bw,
                   void* __restrict__ Cv, int K, int lda, int ldb, int ldc) {
    __shared__ __align__(16) __bf16 As[128 * 64];
    __shared__ __align__(16) __bf16 Bs[128 * 64];

    const int t    = threadIdx.x;
    const int w    = t >> 6;
    const int lane = t & 63;
    const int quad = lane >> 4;
    const int l16  = lane & 15;
    const int wm   = (w >> 1) * 64;
    const int wn   = (w & 1) * 64;

    // XCD-aware swizzle over the linearized grid (x fastest)
    const int nwg  = gridDim.x * gridDim.y;
    const int lin  = blockIdx.y * gridDim.x + blockIdx.x;
    const int swz  = (lin & 7) * (nwg >> 3) + (lin >> 3);
    const int m0   = (swz % gridDim.x) * 128;
    const int n0   = (swz / gridDim.x) * 128;

    const int rl   = lane >> 3;
    const int gl   = lane & 7;

    f32x4 acc[4][4];
#pragma unroll
    for (int i = 0; i < 4; ++i)
#pragma unroll
        for (int j = 0; j < 4; ++j) acc[i][j] = (f32x4){0.f, 0.f, 0.f, 0.f};

    for (int k0 = 0; k0 < K; k0 += 64) {
        __syncthreads();
#pragma unroll
        for (int p = 0; p < 4; ++p) {
            const int rowb = w * 32 + p * 8;
            const int r    = rowb + rl;
            const int gA   = gl ^ rl;
            gload_lds16(A  + (size_t)(m0 + r) * lda + k0 + gA * 8, &As[rowb * 64]);
            gload_lds16(Bw + (size_t)(n0 + r) * ldb + k0 + gA * 8, &Bs[rowb * 64]);
        }
        __syncthreads();
#pragma unroll
        for (int ks = 0; ks < 2; ++ks) {
            const int G = ks * 4 + quad;
            const int gsw = (G ^ (l16 & 7)) * 8;
            bf16x8 af[4], bf[4];
#pragma unroll
            for (int i = 0; i < 4; ++i)
                af[i] = *reinterpret_cast<const bf16x8*>(
                    &As[(wm + i * 16 + l16) * 64 + gsw]);
#pragma unroll
            for (int j = 0; j < 4; ++j)
                bf[j] = *reinterpret_cast<const bf16x8*>(
                    &Bs[(wn + j * 16 + l16) * 64 + gsw]);
#pragma unroll
            for (int i = 0; i < 4; ++i)
#pragma unroll
                for (int j = 0; j < 4; ++j)
                    acc[i][j] = __builtin_amdgcn_mfma_f32_16x16x32_bf16(
                        af[i], bf[j], acc[i][j], 0, 0, 0);
        }
    }
#pragma unroll
    for (int i = 0; i < 4; ++i)
#pragma unroll
        for (int r = 0; r < 4; ++r) {
            size_t m = (size_t)(m0 + wm + i * 16 + quad * 4 + r);
#pragma unroll
            for (int j = 0; j < 4; ++j) {
                int n = n0 + wn + j * 16 + l16;
                if constexpr (OUT_BF16)
                    ((__hip_bfloat16*)Cv)[m * ldc + n] = __float2bfloat16(acc[i][j][r]);
                else
                    ((float*)Cv)[m * ldc + n] = acc[i][j][r];
            }
        }
}

// ---------------------------------------------------------------------------
// RoPE in-place on interleaved qkv: heads 0..15 = Q, 16..23 = K (cols 0..3071
// at stride QKV_LD). One launch covers both. Pair i rotates (2i, 2i+1).
// ---------------------------------------------------------------------------
__global__ void rope_kernel(__hip_bfloat16* __restrict__ xqk,
                            const void* __restrict__ cosv,
                            const void* __restrict__ sinv,
                            const int* __restrict__ dflag_fc,
                            int npairs) {
    int idx = blockIdx.x * blockDim.x + threadIdx.x;
    if (idx >= npairs) return;
    int i  = idx & 63;
    int h  = (idx >> 6) % 24;
    int bs = idx / (64 * 24);
    int s  = bs & (S_LEN - 1);
    float c, sn;
    if (*dflag_fc) {
        c  = __bfloat162float(((const __hip_bfloat16*)cosv)[s * 64 + i]);
        sn = __bfloat162float(((const __hip_bfloat16*)sinv)[s * 64 + i]);
    } else {
        c  = ((const float*)cosv)[s * 64 + i];
        sn = ((const float*)sinv)[s * 64 + i];
    }
    unsigned* p = (unsigned*)(xqk + (size_t)bs * QKV_LD + h * HD_DIM) + i;
    unsigned u = *p;
    float xr = __uint_as_float(u << 16);
    float xi = __uint_as_float(u & 0xFFFF0000u);
    float o0 = xr * c - xi * sn;
    float o1 = xr * sn + xi * c;
    union { __hip_bfloat16 h2[2]; unsigned u32; } out;
    out.h2[0] = __float2bfloat16(o0);
    out.h2[1] = __float2bfloat16(o1);
    *p = out.u32;
}

// ---------------------------------------------------------------------------
// V transpose: qkv v-cols (stride QKV_LD) -> vt [(b*NKV+kv)*128 + d][S].
// ---------------------------------------------------------------------------
__global__ __launch_bounds__(256)
void transpose_v_kernel(const __hip_bfloat16* __restrict__ xv,
                        __hip_bfloat16* __restrict__ vt) {
    __shared__ unsigned short T[32][36];
    const int t  = threadIdx.x;
    const int s0 = blockIdx.x * 32;
    const int d0 = blockIdx.y * 32;
    const int z  = blockIdx.z;           // b*NKV + kv
    const int b  = z >> 3;
    const int kv = z & 7;
    {
        int sr = t >> 3, dc = (t & 7) * 4;
        const unsigned short* p = (const unsigned short*)xv
            + (size_t)(b * S_LEN + s0 + sr) * QKV_LD + kv * 128 + d0 + dc;
        uint2 v = *reinterpret_cast<const uint2*>(p);
        T[sr][dc + 0] = (unsigned short)(v.x & 0xFFFFu);
        T[sr][dc + 1] = (unsigned short)(v.x >> 16);
        T[sr][dc + 2] = (unsigned short)(v.y & 0xFFFFu);
        T[sr][dc + 3] = (unsigned short)(v.y >> 16);
    }
    __syncthreads();
    {
        int dr = t >> 3, sc = (t & 7) * 4;
        unsigned w0 = (unsigned)T[sc + 0][dr] | ((unsigned)T[sc + 1][dr] << 16);
        unsigned w1 = (unsigned)T[sc + 2][dr] | ((unsigned)T[sc + 3][dr] << 16);
        unsigned short* q = (unsigned short*)vt
            + ((size_t)z * 128 + d0 + dr) * S_LEN + s0 + sc;
        uint2 v; v.x = w0; v.y = w1;
        *reinterpret_cast<uint2*>(q) = v;
    }
}

// ---------------------------------------------------------------------------
// MFMA flash attention v10 = v8 (R6, 144.6 us) + deferred-softmax pipeline:
// body(i) = { stage_K(i+1 -> K[p^1]); stage_V(i -> V[p]);
//             QK^T(i) -> sc_cur;  softmax(sc_prev)+PV(i-1) [Vt p^1]; barrier }
// softmax(i-1) [VALU] and QK^T(i) [MFMA+DS] are independent and adjacent in
// one barrier-free region -> compiler interleaves, hiding the VALU phase
// under the MFMA/DS shadow (T15 mechanism). Split K/V stage parity keeps all
// write-after-read hazards barrier-separated:
//   K[p^1] old = K(i-1), last read QK^T(i-1) in body(i-1)  [pre-barrier]
//   V[p]   old = V(i-2), last read PV(i-2)   in body(i-1)  [pre-barrier]
// Register double-banking (scA/scB, mkA/mkB), bodies hand-unrolled x2.
// PV unchanged from R6 (16x16x32, Ps round-trip — R7's in-reg variant
// regressed via Vt b64 bank conflicts).
// ---------------------------------------------------------------------------
__global__ __launch_bounds__(256)
void attn_mfma2_kernel(__hip_bfloat16* qkv,
                       const __hip_bfloat16* __restrict__ vt_g,
                       const unsigned char* __restrict__ msk) {
    __shared__ __align__(16) __bf16 Ks[2][64 * 128];  // 32768 B
    __shared__ __align__(16) __bf16 Vt[2][128 * 64];  // 32768 B
    __shared__ __align__(16) __bf16 Ps[4][16][64];    //  8192 B -> 73728 total

    const int t    = threadIdx.x;
    const int w    = t >> 6;
    const int lane = t & 63;
    const int quad = lane >> 4;
    const int l16  = lane & 15;

    // XCD swizzle: 1024 blocks, chunk=128 -> one XCD covers 4 heads' q-tiles
    const int bid = ((blockIdx.x & 7) << 7) | (blockIdx.x >> 3);
    const int qt  = bid & 31;
    const int h   = (bid >> 5) & (NHQ - 1);
    const int b   = bid >> 9;
    const int kvh = h >> 1;
    const int q0  = qt * 64;

    // ---- Q fragments in registers: wave w owns q rows w*16..w*16+15 ----
    bf16x8 qf[4];
    {
        const __bf16* qrow = (const __bf16*)qkv
            + (size_t)(b * S_LEN + q0 + w * 16 + l16) * QKV_LD + h * 128 + quad * 8;
#pragma unroll
        for (int ks = 0; ks < 4; ++ks)
            qf[ks] = *reinterpret_cast<const bf16x8*>(qrow + ks * 32);
    }

    // per-lane softmax state for q-row l16 (replicated across the 4 quads)
    float m_r = -INFINITY, l_r = 0.f;
    f32x4 o[8];
#pragma unroll
    for (int d0 = 0; d0 < 8; ++d0) o[d0] = (f32x4){0.f, 0.f, 0.f, 0.f};

    const float scale2 = 0.08838834764831845f * 1.4426950408889634f;
    const int gbase = lane & 48;

    // ---- persistent staging pointers (bumped per staged tile) ----
    const __bf16* kp[4];
    const __bf16* vp[4];
    {
        const __bf16* xk = (const __bf16*)qkv + 2048;
        const int krl = lane >> 4, kgl = lane & 15;
        const int vrl = lane >> 3, vgl = lane & 7;
#pragma unroll
        for (int p = 0; p < 4; ++p) {
            const int row = w * 16 + p * 4 + krl;
            kp[p] = xk + (size_t)(b * S_LEN + row) * QKV_LD
                       + kvh * 128 + (kgl ^ (row & 7)) * 8;
        }
#pragma unroll
        for (int p = 0; p < 4; ++p) {
            const int row = w * 32 + p * 8 + vrl;
            vp[p] = (const __bf16*)vt_g
                  + ((size_t)(b * NKV_H + kvh) * 128 + row) * S_LEN
                  + (vgl ^ (row & 7)) * 8;
        }
    }
    const unsigned char* mbase = msk + b * S_LEN;

    f32x4 scA[4], scB[4];
    unsigned mkA[4], mkB[4];

#define STAGE_K(SB) { _Pragma("unroll") \
    for (int p_ = 0; p_ < 4; ++p_) { \
        gload_lds16(kp[p_], &Ks[SB][(w * 16 + p_ * 4) * 128]); \
        kp[p_] += 64 * QKV_LD; } }

#define STAGE_V(SB) { _Pragma("unroll") \
    for (int p_ = 0; p_ < 4; ++p_) { \
        gload_lds16(vp[p_], &Vt[SB][(w * 32 + p_ * 8) * 64]); \
        vp[p_] += 64; } }

#define LOAD_MK(MK, K0) { \
    const unsigned* mp_ = (const unsigned*)(mbase + (K0)); \
    _Pragma("unroll") for (int n_ = 0; n_ < 4; ++n_) MK[n_] = mp_[n_ * 4 + quad]; }

#define QKT(CB, SC) { \
    _Pragma("unroll") for (int n_ = 0; n_ < 4; ++n_) SC[n_] = (f32x4){0.f, 0.f, 0.f, 0.f}; \
    _Pragma("unroll") for (int ks_ = 0; ks_ < 4; ++ks_) { \
        const int G_ = ks_ * 4 + quad; \
        _Pragma("unroll") for (int n_ = 0; n_ < 4; ++n_) { \
            const int row_  = n_ * 16 + l16; \
            const int slot_ = G_ ^ (row_ & 7); \
            bf16x8 kf_ = *reinterpret_cast<const bf16x8*>(&Ks[CB][row_ * 128 + slot_ * 8]); \
            SC[n_] = __builtin_amdgcn_mfma_f32_16x16x32_bf16(kf_, qf[ks_], SC[n_], 0, 0, 0); } } }

#define SMPV(SC, MK, CB) { \
    _Pragma("unroll") for (int n_ = 0; n_ < 4; ++n_) \
        _Pragma("unroll") for (int r_ = 0; r_ < 4; ++r_) \
            SC[n_][r_] = ((MK[n_] >> (r_ * 8)) & 0xFF) ? -INFINITY : SC[n_][r_]; \
    float tq_[4]; \
    _Pragma("unroll") for (int n_ = 0; n_ < 4; ++n_) \
        tq_[n_] = fmaxf(fmaxf(SC[n_][0], SC[n_][1]), fmaxf(SC[n_][2], SC[n_][3])); \
    float rm_ = fmaxf(fmaxf(tq_[0], tq_[1]), fmaxf(tq_[2], tq_[3])); \
    rm_ = fmaxf(rm_, __shfl_xor(rm_, 16, 64)); \
    rm_ = fmaxf(rm_, __shfl_xor(rm_, 32, 64)); \
    bool need_ = (rm_ - m_r) * scale2 > 8.0f; \
    if (__any((int)need_)) { \
        float mn_ = fmaxf(m_r, rm_); \
        float al_ = exp2f((m_r - mn_) * scale2); \
        m_r = mn_; l_r *= al_; \
        float alq_[4]; \
        _Pragma("unroll") for (int r_ = 0; r_ < 4; ++r_) \
            alq_[r_] = __shfl(al_, gbase | (quad * 4 + r_), 64); \
        _Pragma("unroll") for (int d_ = 0; d_ < 8; ++d_) \
            _Pragma("unroll") for (int r_ = 0; r_ < 4; ++r_) o[d_][r_] *= alq_[r_]; } \
    float negm_ = -m_r * scale2; \
    _Pragma("unroll") for (int n_ = 0; n_ < 4; ++n_) { \
        _Pragma("unroll") for (int r_ = 0; r_ < 4; ++r_) { \
            float p_ = exp2f(fmaf(SC[n_][r_], scale2, negm_)); \
            SC[n_][r_] = p_; l_r += p_; } \
        const int kb_    = n_ * 16 + quad * 4; \
        const int gran_  = kb_ >> 3; \
        const int half4_ = kb_ & 4; \
        const int slot_  = gran_ ^ (l16 & 7); \
        bf16x4 pk_; \
        pk_[0] = (__bf16)SC[n_][0]; pk_[1] = (__bf16)SC[n_][1]; \
        pk_[2] = (__bf16)SC[n_][2]; pk_[3] = (__bf16)SC[n_][3]; \
        *reinterpret_cast<bf16x4*>(&Ps[w][l16][slot_ * 8 + half4_]) = pk_; } \
    __builtin_amdgcn_s_setprio(1); \
    _Pragma("unroll") for (int kk_ = 0; kk_ < 64; kk_ += 32) { \
        const int Gp_    = (kk_ >> 3) + quad; \
        const int slotp_ = Gp_ ^ (l16 & 7); \
        bf16x8 af_ = *reinterpret_cast<const bf16x8*>(&Ps[w][l16][slotp_ * 8]); \
        _Pragma("unroll") for (int d_ = 0; d_ < 8; ++d_) { \
            const int row_  = d_ * 16 + l16; \
            const int slot_ = Gp_ ^ (row_ & 7); \
            bf16x8 bf_ = *reinterpret_cast<const bf16x8*>(&Vt[CB][row_ * 64 + slot_ * 8]); \
            o[d_] = __builtin_amdgcn_mfma_f32_16x16x32_bf16(af_, bf_, o[d_], 0, 0, 0); } } \
    __builtin_amdgcn_s_setprio(0); }

    // ---- prologue: K(0) ----
    STAGE_K(0);
    __syncthreads();

    // ---- body 0: stage K(1), V(0); QK^T(0); no softmax/PV yet ----
    STAGE_K(1);
    STAGE_V(0);
    LOAD_MK(mkA, 0);
    QKT(0, scA);
    __syncthreads();

    // ---- bodies 1..30: 15 unrolled pairs (odd p=1, even p=0) ----
    for (int it = 0; it < 15; ++it) {
        const int k0 = it * 128 + 64;
        // body i=2it+1 (p=1): stage K(i+1)->K0, V(i)->V1; QKT(i); SM+PV(i-1)
        STAGE_K(0);
        STAGE_V(1);
        LOAD_MK(mkB, k0);
        QKT(1, scB);
        SMPV(scA, mkA, 0);
        __syncthreads();
        // body i=2it+2 (p=0)
        STAGE_K(1);
        STAGE_V(0);
        LOAD_MK(mkA, k0 + 64);
        QKT(0, scA);
        SMPV(scB, mkB, 1);
        __syncthreads();
    }

    // ---- body 31 (p=1): no K stage; QKT(31); SM+PV(30) ----
    STAGE_V(1);
    LOAD_MK(mkB, 1984);
    QKT(1, scB);
    SMPV(scA, mkA, 0);
    __syncthreads();

    // ---- tail: softmax + PV of tile 31 ----
    SMPV(scB, mkB, 1);

#undef STAGE_K
#undef STAGE_V
#undef LOAD_MK
#undef QKT
#undef SMPV

    // ---- epilogue: reduce l across quads, redistribute to o-rows, write ----
    float ls = l_r;
    ls += __shfl_xor(ls, 16, 64);
    ls += __shfl_xor(ls, 32, 64);
    float invl = 1.f / ls;
    float invq[4];
#pragma unroll
    for (int r = 0; r < 4; ++r)
        invq[r] = __shfl(invl, gbase | (quad * 4 + r), 64);
    __hip_bfloat16* att = qkv;   // own Q cols, own rows only: safe alias
#pragma unroll
    for (int d0 = 0; d0 < 8; ++d0)
#pragma unroll
        for (int r = 0; r < 4; ++r) {
            size_t row = (size_t)(b * S_LEN + q0 + w * 16 + quad * 4 + r);
            att[row * QKV_LD + h * 128 + d0 * 16 + l16] =
                __float2bfloat16(o[d0][r] * invq[r]);
        }
}

// ---------------------------------------------------------------------------
extern "C" void kernel_launch(void* const* d_in, const int* in_sizes, int n_in,
                              void* d_out, int out_size, void* d_ws, size_t ws_size,
                              hipStream_t stream) {
    const void* x  = d_in[0];
    const void* wq = d_in[1];
    const void* wk = d_in[2];
    const void* wv = d_in[3];
    const void* wo = d_in[4];
    const void* fc = d_in[5];
    const void* fs = d_in[6];
    const unsigned char* mraw = (const unsigned char*)d_in[7];

    const int M = BATCH * S_LEN;                                 // 4096
    // ws (32 MB + 8 KB): control, then interleaved qkv [4096][QKV_LD] bf16.
    // att aliases the Q columns; wo-bf16 lands in the k/v columns post-attn.
    char* wsb = (char*)d_ws;
    int* dflag_x  = (int*)wsb;
    int* dflag_fc = (int*)(wsb + 64);
    unsigned char* mnorm = (unsigned char*)(wsb + 128);
    __hip_bfloat16* qkv = (__hip_bfloat16*)(wsb + 8192);

    // d_out (32 MB f32) as staging scratch before its final write:
    // xb [0,16M), combined weights wq|wk|wv [16M,32M); vt reuses [0,8M) later.
    char* dob = (char*)d_out;
    __bf16* xb    = (__bf16*)dob;
    __bf16* wcomb = (__bf16*)(dob + (16u << 20));   // 4096 rows x 2048 cols
    __hip_bfloat16* vt = (__hip_bfloat16*)d_out;

    hipLaunchKernelGGL(prep_kernel, dim3(3), dim3(256), 0, stream,
                       (const unsigned*)x, dflag_x, (const unsigned*)fc, dflag_fc,
                       mraw, mnorm, BATCH * S_LEN);

    hipLaunchKernelGGL(conv_all_kernel, dim3(8192), dim3(256), 0, stream,
                       x, wq, wk, wv, xb, wcomb, dflag_x);

    // ---- fused QKV projection: [4096]x[4096]x[2048], 1024 blocks ----
    hipLaunchKernelGGL((gemm_bt_async<true>), dim3(M / 128, QKV_LD / 128), dim3(256), 0, stream,
                       xb, wcomb, (void*)qkv, DMODEL, DMODEL, DMODEL, QKV_LD);

    // ---- single RoPE over Q+K heads (0..23) ----
    int npairs = M * 24 * (HD_DIM / 2);
    hipLaunchKernelGGL(rope_kernel, dim3(npairs / 256), dim3(256), 0, stream,
                       qkv, fc, fs, dflag_fc, npairs);

    hipLaunchKernelGGL(transpose_v_kernel, dim3(S_LEN / 32, HD_DIM / 32, BATCH * NKV_H),
                       dim3(256), 0, stream, qkv + 3072, vt);

    hipLaunchKernelGGL(attn_mfma2_kernel, dim3(BATCH * NHQ * (S_LEN / 64)), dim3(256), 0, stream,
                       qkv, vt, mnorm);

    // ---- wo -> bf16 into dead k/v columns (after attn finished reading K) ----
    hipLaunchKernelGGL(conv_bf16_strided_kernel, dim3((DMODEL * DMODEL / 8) / 256), dim3(256), 0, stream,
                       wo, (__bf16*)qkv + 2048, DMODEL * DMODEL / 8, dflag_x);

    // ---- O-projection: A = att (Q cols, lda=QKV_LD), B = wo (ldb=QKV_LD) ----
    hipLaunchKernelGGL((gemm_bt_async<false>), dim3(M / 128, DMODEL / 128), dim3(256), 0, stream,
                       (const __bf16*)qkv, (const __bf16*)qkv + 2048, d_out,
                       DMODEL, QKV_LD, QKV_LD, DMODEL);
}